// Round 1
// baseline (479.306 us; speedup 1.0000x reference)
//
#include <hip/hip_runtime.h>
#include <hip/hip_bf16.h>

#define B 1024

// ---------------- K1: conv 1->4, 3x3, stride2, pad1, ReLU. (B,1,64,64)->(B,4,32,32)
__global__ __launch_bounds__(256) void k_pre1(const float* __restrict__ x,
                                              const float* __restrict__ w,
                                              const float* __restrict__ bias,
                                              float* __restrict__ out) {
    int idx = blockIdx.x * blockDim.x + threadIdx.x;
    if (idx >= B * 32 * 32) return;
    int b = idx >> 10;
    int rem = idx & 1023;
    int oy = rem >> 5, ox = rem & 31;
    const float* xin = x + b * 4096;
    float a0 = bias[0], a1 = bias[1], a2 = bias[2], a3 = bias[3];
#pragma unroll
    for (int ky = 0; ky < 3; ++ky) {
        int iy = 2 * oy - 1 + ky;
        if (iy < 0 || iy >= 64) continue;
#pragma unroll
        for (int kx = 0; kx < 3; ++kx) {
            int ix = 2 * ox - 1 + kx;
            if (ix < 0 || ix >= 64) continue;
            float v = xin[iy * 64 + ix];
            int k = ky * 3 + kx;
            a0 += w[k] * v;
            a1 += w[9 + k] * v;
            a2 += w[18 + k] * v;
            a3 += w[27 + k] * v;
        }
    }
    float* o = out + b * 4096 + oy * 32 + ox;
    o[0]    = fmaxf(a0, 0.f);
    o[1024] = fmaxf(a1, 0.f);
    o[2048] = fmaxf(a2, 0.f);
    o[3072] = fmaxf(a3, 0.f);
}

// ---------------- K2: conv 4->4, 3x3, stride2, pad1, ReLU. (B,4,32,32)->(B,4,16,16)
__global__ __launch_bounds__(256) void k_pre2(const float* __restrict__ in,
                                              const float* __restrict__ w,
                                              const float* __restrict__ bias,
                                              float* __restrict__ out) {
    int idx = blockIdx.x * blockDim.x + threadIdx.x;
    if (idx >= B * 16 * 16) return;
    int b = idx >> 8;
    int rem = idx & 255;
    int oy = rem >> 4, ox = rem & 15;
    const float* xin = in + b * 4096;
    float acc[4] = {bias[0], bias[1], bias[2], bias[3]};
#pragma unroll
    for (int ci = 0; ci < 4; ++ci) {
#pragma unroll
        for (int ky = 0; ky < 3; ++ky) {
            int iy = 2 * oy - 1 + ky;
            if (iy < 0 || iy >= 32) continue;
#pragma unroll
            for (int kx = 0; kx < 3; ++kx) {
                int ix = 2 * ox - 1 + kx;
                if (ix < 0 || ix >= 32) continue;
                float v = xin[ci * 1024 + iy * 32 + ix];
#pragma unroll
                for (int co = 0; co < 4; ++co)
                    acc[co] += w[((co * 4 + ci) * 3 + ky) * 3 + kx] * v;
            }
        }
    }
#pragma unroll
    for (int co = 0; co < 4; ++co)
        out[b * 1024 + co * 256 + oy * 16 + ox] = fmaxf(acc[co], 0.f);
}

// ---------------- K3: conv 4->4, 3x3, stride1, pad0, no relu. (B,4,16,16)->(B,4,14,14)
__global__ __launch_bounds__(256) void k_pre3(const float* __restrict__ in,
                                              const float* __restrict__ w,
                                              const float* __restrict__ bias,
                                              float* __restrict__ out) {
    int idx = blockIdx.x * blockDim.x + threadIdx.x;
    if (idx >= B * 14 * 14) return;
    int b = idx / 196;
    int rem = idx % 196;
    int oy = rem / 14, ox = rem % 14;
    const float* xin = in + b * 1024;
    float acc[4] = {bias[0], bias[1], bias[2], bias[3]};
#pragma unroll
    for (int ci = 0; ci < 4; ++ci) {
#pragma unroll
        for (int ky = 0; ky < 3; ++ky) {
#pragma unroll
            for (int kx = 0; kx < 3; ++kx) {
                float v = xin[ci * 256 + (oy + ky) * 16 + (ox + kx)];
#pragma unroll
                for (int co = 0; co < 4; ++co)
                    acc[co] += w[((co * 4 + ci) * 3 + ky) * 3 + kx] * v;
            }
        }
    }
#pragma unroll
    for (int co = 0; co < 4; ++co)
        out[b * 784 + co * 196 + oy * 14 + ox] = acc[co];
}

// ---------------- K4: quanv closed form. h3 (B,4,14,14) -> q (B,16,7,7)
// z_w = cos(theta_w)cos(x_w) - sin(theta_w)sin(phi_w)sin(x_w); <Z_w> = prod_{v<=w} z_v
__global__ __launch_bounds__(256) void k_quanv(const float* __restrict__ h3,
                                               const float* __restrict__ qw,
                                               float* __restrict__ q) {
    int idx = blockIdx.x * blockDim.x + threadIdx.x;
    if (idx >= B * 4 * 49) return;
    int b = idx / 196;
    int rem = idx % 196;
    int c = rem / 49;
    int pos = rem % 49;
    int oh = pos / 7, ow = pos % 7;
    const float* hp = h3 + b * 784 + c * 196;
    float xv[4];
    xv[0] = hp[(2 * oh) * 14 + 2 * ow];
    xv[1] = hp[(2 * oh) * 14 + 2 * ow + 1];
    xv[2] = hp[(2 * oh + 1) * 14 + 2 * ow];
    xv[3] = hp[(2 * oh + 1) * 14 + 2 * ow + 1];
    float prod = 1.f;
    float* qo = q + b * 784 + c * 4 * 49 + pos;
#pragma unroll
    for (int w = 0; w < 4; ++w) {
        float phi = qw[w * 3 + 0];
        float theta = qw[w * 3 + 1];
        float st, ct, sx, cx;
        __sincosf(theta, &st, &ct);
        float sp = __sinf(phi);
        __sincosf(xv[w], &sx, &cx);
        float z = ct * cx - st * sp * sx;
        prod *= z;
        qo[w * 49] = prod;
    }
}

// ---------------- K5: conv1 16->32 3x3 p1 + GroupNorm(8) + ReLU. block per sample.
__global__ __launch_bounds__(256) void k_conv1_gn(const float* __restrict__ q,
                                                  const float* __restrict__ w,
                                                  const float* __restrict__ bias,
                                                  const float* __restrict__ gw,
                                                  const float* __restrict__ gb,
                                                  float* __restrict__ out) {
    __shared__ float s_in[784];
    __shared__ float s_out[1568];
    __shared__ float s_mu[8], s_rs[8];
    int b = blockIdx.x, tid = threadIdx.x;
    for (int i = tid; i < 784; i += 256) s_in[i] = q[b * 784 + i];
    __syncthreads();
    for (int o = tid; o < 1568; o += 256) {
        int co = o / 49, pos = o % 49;
        int y = pos / 7, xx = pos % 7;
        float acc = bias[co];
        const float* wc = w + co * 144;
        for (int ci = 0; ci < 16; ++ci) {
            const float* sc = s_in + ci * 49;
            const float* wci = wc + ci * 9;
#pragma unroll
            for (int ky = 0; ky < 3; ++ky) {
                int iy = y + ky - 1;
                if (iy < 0 || iy >= 7) continue;
#pragma unroll
                for (int kx = 0; kx < 3; ++kx) {
                    int ix = xx + kx - 1;
                    if (ix < 0 || ix >= 7) continue;
                    acc += wci[ky * 3 + kx] * sc[iy * 7 + ix];
                }
            }
        }
        s_out[o] = acc;
    }
    __syncthreads();
    // GroupNorm stats: 8 groups x (4ch*49=196) contiguous; 32 lanes per group
    int g = tid >> 5, lane = tid & 31;
    float sum = 0.f, ssq = 0.f;
    for (int i = lane; i < 196; i += 32) {
        float v = s_out[g * 196 + i];
        sum += v;
        ssq += v * v;
    }
#pragma unroll
    for (int m = 16; m >= 1; m >>= 1) {
        sum += __shfl_xor(sum, m);
        ssq += __shfl_xor(ssq, m);
    }
    if (lane == 0) {
        float mu = sum * (1.f / 196.f);
        float var = ssq * (1.f / 196.f) - mu * mu;
        s_mu[g] = mu;
        s_rs[g] = rsqrtf(var + 1e-5f);
    }
    __syncthreads();
    for (int o = tid; o < 1568; o += 256) {
        int co = o / 49;
        int gg = co >> 2;
        float v = (s_out[o] - s_mu[gg]) * s_rs[gg] * gw[co] + gb[co];
        out[b * 1568 + o] = fmaxf(v, 0.f);
    }
}

// ---------------- K6: conv2 32->64 3x3 p1 + GroupNorm(8) + ReLU + maxpool2 -> (B,64,3,3)
__global__ __launch_bounds__(256) void k_conv2_gn_pool(const float* __restrict__ in,
                                                       const float* __restrict__ w,
                                                       const float* __restrict__ bias,
                                                       const float* __restrict__ gw,
                                                       const float* __restrict__ gb,
                                                       float* __restrict__ out) {
    __shared__ float s_in[1568];
    __shared__ float s_out[3136];
    __shared__ float s_mu[8], s_rs[8];
    int b = blockIdx.x, tid = threadIdx.x;
    for (int i = tid; i < 1568; i += 256) s_in[i] = in[b * 1568 + i];
    __syncthreads();
    for (int o = tid; o < 3136; o += 256) {
        int co = o / 49, pos = o % 49;
        int y = pos / 7, xx = pos % 7;
        float acc = bias[co];
        const float* wc = w + co * 288;
        for (int ci = 0; ci < 32; ++ci) {
            const float* sc = s_in + ci * 49;
            const float* wci = wc + ci * 9;
#pragma unroll
            for (int ky = 0; ky < 3; ++ky) {
                int iy = y + ky - 1;
                if (iy < 0 || iy >= 7) continue;
#pragma unroll
                for (int kx = 0; kx < 3; ++kx) {
                    int ix = xx + kx - 1;
                    if (ix < 0 || ix >= 7) continue;
                    acc += wci[ky * 3 + kx] * sc[iy * 7 + ix];
                }
            }
        }
        s_out[o] = acc;
    }
    __syncthreads();
    // GN: 8 groups x (8ch*49=392) contiguous
    int g = tid >> 5, lane = tid & 31;
    float sum = 0.f, ssq = 0.f;
    for (int i = lane; i < 392; i += 32) {
        float v = s_out[g * 392 + i];
        sum += v;
        ssq += v * v;
    }
#pragma unroll
    for (int m = 16; m >= 1; m >>= 1) {
        sum += __shfl_xor(sum, m);
        ssq += __shfl_xor(ssq, m);
    }
    if (lane == 0) {
        float mu = sum * (1.f / 392.f);
        float var = ssq * (1.f / 392.f) - mu * mu;
        s_mu[g] = mu;
        s_rs[g] = rsqrtf(var + 1e-5f);
    }
    __syncthreads();
    for (int o = tid; o < 3136; o += 256) {
        int co = o / 49;
        int gg = co >> 3;
        float v = (s_out[o] - s_mu[gg]) * s_rs[gg] * gw[co] + gb[co];
        s_out[o] = fmaxf(v, 0.f);
    }
    __syncthreads();
    // maxpool 2x2 on 7x7 -> 3x3 (uses rows/cols 0..5)
    for (int i = tid; i < 64 * 9; i += 256) {
        int co = i / 9, p = i % 9;
        int py = p / 3, px = p % 3;
        const float* sc = s_out + co * 49 + 2 * py * 7 + 2 * px;
        float m0 = fmaxf(sc[0], sc[1]);
        float m1 = fmaxf(sc[7], sc[8]);
        out[b * 576 + i] = fmaxf(m0, m1);
    }
}

// ---------------- K7: fc1 576->128 + ReLU + fc2 128->10. block per sample, 128 threads.
__global__ __launch_bounds__(128) void k_fc(const float* __restrict__ p2,
                                            const float* __restrict__ w1,
                                            const float* __restrict__ b1,
                                            const float* __restrict__ w2,
                                            const float* __restrict__ b2,
                                            float* __restrict__ out) {
    __shared__ float s_p[576];
    __shared__ float s_f[128];
    int b = blockIdx.x, tid = threadIdx.x;
    for (int i = tid; i < 576; i += 128) s_p[i] = p2[b * 576 + i];
    __syncthreads();
    {
        float acc = b1[tid];
        const float4* wr = reinterpret_cast<const float4*>(w1 + tid * 576);
        const float4* sp = reinterpret_cast<const float4*>(s_p);
#pragma unroll 4
        for (int j = 0; j < 144; ++j) {
            float4 a = wr[j], c = sp[j];
            acc += a.x * c.x + a.y * c.y + a.z * c.z + a.w * c.w;
        }
        s_f[tid] = fmaxf(acc, 0.f);
    }
    __syncthreads();
    if (tid < 10) {
        float acc = b2[tid];
        const float* wr = w2 + tid * 128;
#pragma unroll 8
        for (int j = 0; j < 128; ++j) acc += wr[j] * s_f[j];
        out[b * 10 + tid] = acc;
    }
}

extern "C" void kernel_launch(void* const* d_in, const int* in_sizes, int n_in,
                              void* d_out, int out_size, void* d_ws, size_t ws_size,
                              hipStream_t stream) {
    const float* x       = (const float*)d_in[0];
    const float* pre_w1  = (const float*)d_in[1];
    const float* pre_b1  = (const float*)d_in[2];
    const float* pre_w2  = (const float*)d_in[3];
    const float* pre_b2  = (const float*)d_in[4];
    const float* pre_w3  = (const float*)d_in[5];
    const float* pre_b3  = (const float*)d_in[6];
    const float* qweights= (const float*)d_in[7];
    const float* conv1_w = (const float*)d_in[8];
    const float* conv1_b = (const float*)d_in[9];
    const float* gn1_w   = (const float*)d_in[10];
    const float* gn1_b   = (const float*)d_in[11];
    const float* conv2_w = (const float*)d_in[12];
    const float* conv2_b = (const float*)d_in[13];
    const float* gn2_w   = (const float*)d_in[14];
    const float* gn2_b   = (const float*)d_in[15];
    const float* fc1_w   = (const float*)d_in[16];
    const float* fc1_b   = (const float*)d_in[17];
    const float* fc2_w   = (const float*)d_in[18];
    const float* fc2_b   = (const float*)d_in[19];
    float* out = (float*)d_out;

    // workspace regions (floats), with liveness-based reuse:
    //  R0 [0, 4194304): h1 (K1-K2), then q (K4-K5)
    //  R1 [4194304, 5799936): h2 (K2-K3), then g1 (K5-K6)
    //  R2 [5799936, 6602752): h3 (K3-K4), then p2 (K6-K7)
    float* ws = (float*)d_ws;
    float* h1 = ws;
    float* qb = ws;
    float* h2 = ws + 4194304;
    float* g1 = ws + 4194304;
    float* h3 = ws + 5799936;
    float* p2 = ws + 5799936;

    k_pre1<<<(B * 32 * 32 + 255) / 256, 256, 0, stream>>>(x, pre_w1, pre_b1, h1);
    k_pre2<<<(B * 16 * 16 + 255) / 256, 256, 0, stream>>>(h1, pre_w2, pre_b2, h2);
    k_pre3<<<(B * 14 * 14 + 255) / 256, 256, 0, stream>>>(h2, pre_w3, pre_b3, h3);
    k_quanv<<<(B * 4 * 49 + 255) / 256, 256, 0, stream>>>(h3, qweights, qb);
    k_conv1_gn<<<B, 256, 0, stream>>>(qb, conv1_w, conv1_b, gn1_w, gn1_b, g1);
    k_conv2_gn_pool<<<B, 256, 0, stream>>>(g1, conv2_w, conv2_b, gn2_w, gn2_b, p2);
    k_fc<<<B, 128, 0, stream>>>(p2, fc1_w, fc1_b, fc2_w, fc2_b, out);
}

// Round 2
// 271.111 us; speedup vs baseline: 1.7679x; 1.7679x over previous
//
#include <hip/hip_runtime.h>
#include <hip/hip_bf16.h>

#define B 1024

// ---------------- K1: conv 1->4, 3x3, stride2, pad1, ReLU. (B,1,64,64)->(B,4,32,32)
__global__ __launch_bounds__(256) void k_pre1(const float* __restrict__ x,
                                              const float* __restrict__ w,
                                              const float* __restrict__ bias,
                                              float* __restrict__ out) {
    int idx = blockIdx.x * blockDim.x + threadIdx.x;
    if (idx >= B * 32 * 32) return;
    int b = idx >> 10;
    int rem = idx & 1023;
    int oy = rem >> 5, ox = rem & 31;
    const float* xin = x + b * 4096;
    float a0 = bias[0], a1 = bias[1], a2 = bias[2], a3 = bias[3];
#pragma unroll
    for (int ky = 0; ky < 3; ++ky) {
        int iy = 2 * oy - 1 + ky;
        if (iy < 0 || iy >= 64) continue;
#pragma unroll
        for (int kx = 0; kx < 3; ++kx) {
            int ix = 2 * ox - 1 + kx;
            if (ix < 0 || ix >= 64) continue;
            float v = xin[iy * 64 + ix];
            int k = ky * 3 + kx;
            a0 += w[k] * v;
            a1 += w[9 + k] * v;
            a2 += w[18 + k] * v;
            a3 += w[27 + k] * v;
        }
    }
    float* o = out + b * 4096 + oy * 32 + ox;
    o[0]    = fmaxf(a0, 0.f);
    o[1024] = fmaxf(a1, 0.f);
    o[2048] = fmaxf(a2, 0.f);
    o[3072] = fmaxf(a3, 0.f);
}

// ---------------- K2: conv 4->4, 3x3, stride2, pad1, ReLU. (B,4,32,32)->(B,4,16,16)
__global__ __launch_bounds__(256) void k_pre2(const float* __restrict__ in,
                                              const float* __restrict__ w,
                                              const float* __restrict__ bias,
                                              float* __restrict__ out) {
    int idx = blockIdx.x * blockDim.x + threadIdx.x;
    if (idx >= B * 16 * 16) return;
    int b = idx >> 8;
    int rem = idx & 255;
    int oy = rem >> 4, ox = rem & 15;
    const float* xin = in + b * 4096;
    float acc[4] = {bias[0], bias[1], bias[2], bias[3]};
#pragma unroll
    for (int ci = 0; ci < 4; ++ci) {
#pragma unroll
        for (int ky = 0; ky < 3; ++ky) {
            int iy = 2 * oy - 1 + ky;
            if (iy < 0 || iy >= 32) continue;
#pragma unroll
            for (int kx = 0; kx < 3; ++kx) {
                int ix = 2 * ox - 1 + kx;
                if (ix < 0 || ix >= 32) continue;
                float v = xin[ci * 1024 + iy * 32 + ix];
#pragma unroll
                for (int co = 0; co < 4; ++co)
                    acc[co] += w[((co * 4 + ci) * 3 + ky) * 3 + kx] * v;
            }
        }
    }
#pragma unroll
    for (int co = 0; co < 4; ++co)
        out[b * 1024 + co * 256 + oy * 16 + ox] = fmaxf(acc[co], 0.f);
}

// ---------------- K3: conv 4->4, 3x3, stride1, pad0, no relu. (B,4,16,16)->(B,4,14,14)
__global__ __launch_bounds__(256) void k_pre3(const float* __restrict__ in,
                                              const float* __restrict__ w,
                                              const float* __restrict__ bias,
                                              float* __restrict__ out) {
    int idx = blockIdx.x * blockDim.x + threadIdx.x;
    if (idx >= B * 14 * 14) return;
    int b = idx / 196;
    int rem = idx % 196;
    int oy = rem / 14, ox = rem % 14;
    const float* xin = in + b * 1024;
    float acc[4] = {bias[0], bias[1], bias[2], bias[3]};
#pragma unroll
    for (int ci = 0; ci < 4; ++ci) {
#pragma unroll
        for (int ky = 0; ky < 3; ++ky) {
#pragma unroll
            for (int kx = 0; kx < 3; ++kx) {
                float v = xin[ci * 256 + (oy + ky) * 16 + (ox + kx)];
#pragma unroll
                for (int co = 0; co < 4; ++co)
                    acc[co] += w[((co * 4 + ci) * 3 + ky) * 3 + kx] * v;
            }
        }
    }
#pragma unroll
    for (int co = 0; co < 4; ++co)
        out[b * 784 + co * 196 + oy * 14 + ox] = acc[co];
}

// ---------------- K4: quanv closed form. h3 (B,4,14,14) -> qb (B,16ch,[64-pad]) padded planes
// z_w = cos(theta_w)cos(x_w) - sin(theta_w)sin(phi_w)sin(x_w); <Z_w> = prod_{v<=w} z_v
__global__ __launch_bounds__(256) void k_quanv(const float* __restrict__ h3,
                                               const float* __restrict__ qw,
                                               float* __restrict__ q) {
    int idx = blockIdx.x * blockDim.x + threadIdx.x;
    if (idx >= B * 4 * 49) return;
    int b = idx / 196;
    int rem = idx % 196;
    int c = rem / 49;
    int pos = rem % 49;
    int oh = pos / 7, ow = pos % 7;
    const float* hp = h3 + b * 784 + c * 196;
    float xv[4];
    xv[0] = hp[(2 * oh) * 14 + 2 * ow];
    xv[1] = hp[(2 * oh) * 14 + 2 * ow + 1];
    xv[2] = hp[(2 * oh + 1) * 14 + 2 * ow];
    xv[3] = hp[(2 * oh + 1) * 14 + 2 * ow + 1];
    float prod = 1.f;
    float* qo = q + b * 1024 + c * 4 * 64 + pos;   // padded: 64 floats per channel plane
#pragma unroll
    for (int w = 0; w < 4; ++w) {
        float phi = qw[w * 3 + 0];
        float theta = qw[w * 3 + 1];
        float st, ct, sx, cx;
        __sincosf(theta, &st, &ct);
        float sp = __sinf(phi);
        __sincosf(xv[w], &sx, &cx);
        float z = ct * cx - st * sp * sx;
        prod *= z;
        qo[w * 64] = prod;
    }
}

// ---------------- K4b: weight transposes. conv1_w (32,16,3,3)->tw1[ci][k][co32];
//                                          conv2_w (64,32,3,3)->tw2[ci][k][co64]
__global__ __launch_bounds__(256) void k_transpose_w(const float* __restrict__ cw1,
                                                     const float* __restrict__ cw2,
                                                     float* __restrict__ tw1,
                                                     float* __restrict__ tw2) {
    int i = blockIdx.x * 256 + threadIdx.x;
    if (i < 4608) {
        int co = i & 31; int rest = i >> 5; int k = rest % 9; int ci = rest / 9;
        tw1[i] = cw1[(co * 16 + ci) * 9 + k];
    }
    if (i < 18432) {
        int co = i & 63; int rest = i >> 6; int k = rest % 9; int ci = rest / 9;
        tw2[i] = cw2[(co * 32 + ci) * 9 + k];
    }
}

// --------- register-resident helpers (all indices compile-time after unroll)
__device__ __forceinline__ void load_plane(const float* __restrict__ p, float* dst) {
#pragma unroll
    for (int j = 0; j < 13; ++j) {
        float4 v = reinterpret_cast<const float4*>(p)[j];
        dst[4 * j] = v.x; dst[4 * j + 1] = v.y; dst[4 * j + 2] = v.z; dst[4 * j + 3] = v.w;
    }
}

template <int STRIDE>
__device__ __forceinline__ void load_w9(const float* __restrict__ p, float* w) {
#pragma unroll
    for (int k = 0; k < 9; ++k) w[k] = p[k * STRIDE];
}

__device__ __forceinline__ void conv_acc(const float* pl, const float* w, float* acc) {
#pragma unroll
    for (int oy = 0; oy < 7; ++oy)
#pragma unroll
        for (int ox = 0; ox < 7; ++ox)
#pragma unroll
            for (int ky = 0; ky < 3; ++ky) {
                int iy = oy + ky - 1;
                if (iy < 0 || iy >= 7) continue;
#pragma unroll
                for (int kx = 0; kx < 3; ++kx) {
                    int ix = ox + kx - 1;
                    if (ix < 0 || ix >= 7) continue;
                    acc[oy * 7 + ox] += w[ky * 3 + kx] * pl[iy * 7 + ix];
                }
            }
}

// ---------------- K5: conv1 16->32 + GN(8 groups of 4ch) + ReLU. wave=sample, lane=co.
// in: qb padded [b][16][64]; out: g1 padded [b][32][64]
__global__ __launch_bounds__(64) void k_conv1_fused(const float* __restrict__ qb,
                                                    const float* __restrict__ tw1,
                                                    const float* __restrict__ bias,
                                                    const float* __restrict__ gw,
                                                    const float* __restrict__ gb,
                                                    float* __restrict__ g1) {
    int b = blockIdx.x;
    int co = threadIdx.x;
    if (co >= 32) return;
    const float* pin = qb + b * 1024;
    float acc[49];
    float bco = bias[co];
#pragma unroll
    for (int p = 0; p < 49; ++p) acc[p] = bco;

    float pa[52], pb[52], wa[9], wb[9];
    load_plane(pin, pa);
    load_w9<32>(tw1 + co, wa);
    for (int ci = 0; ci < 16; ci += 2) {
        load_plane(pin + (ci + 1) * 64, pb);
        load_w9<32>(tw1 + (ci + 1) * 288 + co, wb);
        conv_acc(pa, wa, acc);
        if (ci + 2 < 16) {
            load_plane(pin + (ci + 2) * 64, pa);
            load_w9<32>(tw1 + (ci + 2) * 288 + co, wa);
        }
        conv_acc(pb, wb, acc);
    }
    // GroupNorm over 4 adjacent channels x 49 positions (lanes co: group co>>2)
    float sum = 0.f, ssq = 0.f;
#pragma unroll
    for (int p = 0; p < 49; ++p) { sum += acc[p]; ssq += acc[p] * acc[p]; }
    sum += __shfl_xor(sum, 1); ssq += __shfl_xor(ssq, 1);
    sum += __shfl_xor(sum, 2); ssq += __shfl_xor(ssq, 2);
    float mu = sum * (1.f / 196.f);
    float var = ssq * (1.f / 196.f) - mu * mu;
    float rs = rsqrtf(var + 1e-5f);
    float ga = gw[co] * rs;
    float be = gb[co] - mu * ga;
    float* o = g1 + b * 2048 + co * 64;
#pragma unroll
    for (int p = 0; p < 49; ++p) o[p] = fmaxf(acc[p] * ga + be, 0.f);
}

// ---------------- K6: conv2 32->64 + GN(8 groups of 8ch) + ReLU + maxpool2 -> (B,64,3,3)
// in: g1 padded [b][32][64]; out: p2 [b][64][9]
__global__ __launch_bounds__(64) void k_conv2_fused(const float* __restrict__ g1,
                                                    const float* __restrict__ tw2,
                                                    const float* __restrict__ bias,
                                                    const float* __restrict__ gw,
                                                    const float* __restrict__ gb,
                                                    float* __restrict__ out) {
    int b = blockIdx.x;
    int co = threadIdx.x;  // 0..63
    const float* pin = g1 + b * 2048;
    float acc[49];
    float bco = bias[co];
#pragma unroll
    for (int p = 0; p < 49; ++p) acc[p] = bco;

    float pa[52], pb[52], wa[9], wb[9];
    load_plane(pin, pa);
    load_w9<64>(tw2 + co, wa);
    for (int ci = 0; ci < 32; ci += 2) {
        load_plane(pin + (ci + 1) * 64, pb);
        load_w9<64>(tw2 + (ci + 1) * 576 + co, wb);
        conv_acc(pa, wa, acc);
        if (ci + 2 < 32) {
            load_plane(pin + (ci + 2) * 64, pa);
            load_w9<64>(tw2 + (ci + 2) * 576 + co, wa);
        }
        conv_acc(pb, wb, acc);
    }
    // GroupNorm over 8 adjacent channels x 49 positions (group co>>3)
    float sum = 0.f, ssq = 0.f;
#pragma unroll
    for (int p = 0; p < 49; ++p) { sum += acc[p]; ssq += acc[p] * acc[p]; }
    sum += __shfl_xor(sum, 1); ssq += __shfl_xor(ssq, 1);
    sum += __shfl_xor(sum, 2); ssq += __shfl_xor(ssq, 2);
    sum += __shfl_xor(sum, 4); ssq += __shfl_xor(ssq, 4);
    float mu = sum * (1.f / 392.f);
    float var = ssq * (1.f / 392.f) - mu * mu;
    float rs = rsqrtf(var + 1e-5f);
    float ga = gw[co] * rs;
    float be = gb[co] - mu * ga;
#pragma unroll
    for (int p = 0; p < 49; ++p) acc[p] = fmaxf(acc[p] * ga + be, 0.f);
    // maxpool 2x2 (rows/cols 0..5) -> 3x3
    float* o = out + b * 576 + co * 9;
#pragma unroll
    for (int py = 0; py < 3; ++py)
#pragma unroll
        for (int px = 0; px < 3; ++px) {
            int p0 = (2 * py) * 7 + 2 * px;
            float m = fmaxf(fmaxf(acc[p0], acc[p0 + 1]), fmaxf(acc[p0 + 7], acc[p0 + 8]));
            o[py * 3 + px] = m;
        }
}

// ---------------- K7: fc1 576->128 + ReLU + fc2 128->10. block per sample, 128 threads.
__global__ __launch_bounds__(128) void k_fc(const float* __restrict__ p2,
                                            const float* __restrict__ w1,
                                            const float* __restrict__ b1,
                                            const float* __restrict__ w2,
                                            const float* __restrict__ b2,
                                            float* __restrict__ out) {
    __shared__ float s_p[576];
    __shared__ float s_f[128];
    int b = blockIdx.x, tid = threadIdx.x;
    for (int i = tid; i < 576; i += 128) s_p[i] = p2[b * 576 + i];
    __syncthreads();
    {
        float acc = b1[tid];
        const float4* wr = reinterpret_cast<const float4*>(w1 + tid * 576);
        const float4* sp = reinterpret_cast<const float4*>(s_p);
#pragma unroll 4
        for (int j = 0; j < 144; ++j) {
            float4 a = wr[j], c = sp[j];
            acc += a.x * c.x + a.y * c.y + a.z * c.z + a.w * c.w;
        }
        s_f[tid] = fmaxf(acc, 0.f);
    }
    __syncthreads();
    if (tid < 10) {
        float acc = b2[tid];
        const float* wr = w2 + tid * 128;
#pragma unroll 8
        for (int j = 0; j < 128; ++j) acc += wr[j] * s_f[j];
        out[b * 10 + tid] = acc;
    }
}

extern "C" void kernel_launch(void* const* d_in, const int* in_sizes, int n_in,
                              void* d_out, int out_size, void* d_ws, size_t ws_size,
                              hipStream_t stream) {
    const float* x       = (const float*)d_in[0];
    const float* pre_w1  = (const float*)d_in[1];
    const float* pre_b1  = (const float*)d_in[2];
    const float* pre_w2  = (const float*)d_in[3];
    const float* pre_b2  = (const float*)d_in[4];
    const float* pre_w3  = (const float*)d_in[5];
    const float* pre_b3  = (const float*)d_in[6];
    const float* qweights= (const float*)d_in[7];
    const float* conv1_w = (const float*)d_in[8];
    const float* conv1_b = (const float*)d_in[9];
    const float* gn1_w   = (const float*)d_in[10];
    const float* gn1_b   = (const float*)d_in[11];
    const float* conv2_w = (const float*)d_in[12];
    const float* conv2_b = (const float*)d_in[13];
    const float* gn2_w   = (const float*)d_in[14];
    const float* gn2_b   = (const float*)d_in[15];
    const float* fc1_w   = (const float*)d_in[16];
    const float* fc1_b   = (const float*)d_in[17];
    const float* fc2_w   = (const float*)d_in[18];
    const float* fc2_b   = (const float*)d_in[19];
    float* out = (float*)d_out;

    // workspace regions (floats), liveness-based reuse:
    //  A [0, 4194304): h1 (K1-K2); later qb@A (K4-K5, 1.05M) + g1@A+1048576 (K5-K6, 2.10M)
    //  B [4194304, 5242880): h2 (K2-K3); later p2 (K6-K7, 0.59M)
    //  C [5242880, 6045696): h3 (K3-K4)
    //  D [6045696, +23040): tw1, tw2 (K0-K6)
    float* ws = (float*)d_ws;
    float* h1 = ws;
    float* qb = ws;
    float* g1 = ws + 1048576;
    float* h2 = ws + 4194304;
    float* p2 = ws + 4194304;
    float* h3 = ws + 5242880;
    float* tw1 = ws + 6045696;
    float* tw2 = ws + 6045696 + 4608;

    k_transpose_w<<<72, 256, 0, stream>>>(conv1_w, conv2_w, tw1, tw2);
    k_pre1<<<(B * 32 * 32 + 255) / 256, 256, 0, stream>>>(x, pre_w1, pre_b1, h1);
    k_pre2<<<(B * 16 * 16 + 255) / 256, 256, 0, stream>>>(h1, pre_w2, pre_b2, h2);
    k_pre3<<<(B * 14 * 14 + 255) / 256, 256, 0, stream>>>(h2, pre_w3, pre_b3, h3);
    k_quanv<<<(B * 4 * 49 + 255) / 256, 256, 0, stream>>>(h3, qweights, qb);
    k_conv1_fused<<<B, 64, 0, stream>>>(qb, tw1, conv1_b, gn1_w, gn1_b, g1);
    k_conv2_fused<<<B, 64, 0, stream>>>(g1, tw2, conv2_b, gn2_w, gn2_b, p2);
    k_fc<<<B, 128, 0, stream>>>(p2, fc1_w, fc1_b, fc2_w, fc2_b, out);
}